// Round 9
// baseline (305.039 us; speedup 1.0000x reference)
//
#include <hip/hip_runtime.h>
#include <math.h>

#define NHEADS 16
#define HD 64
#define SEQ 2048
#define BATCH 2
#define DM 1024
#define MTOT (BATCH*SEQ)   // 4096
#define LDP 72             // pt row stride (halfwords): b128 reads conflict-free

typedef __bf16 bf16x8 __attribute__((ext_vector_type(8)));
typedef __bf16 bf16x4 __attribute__((ext_vector_type(4)));
typedef float  f32x4  __attribute__((ext_vector_type(4)));

#define LOG2E 1.4426950408889634f

// async global->LDS, 16B per lane; LDS side is wave-uniform base + lane*16
#define GLD16(gp, lp) __builtin_amdgcn_global_load_lds( \
    (const __attribute__((address_space(1))) void*)(gp), \
    (__attribute__((address_space(3))) void*)(lp), 16, 0, 0)

// ---------------- cast: x -> bf16, [Wq;Wk;Wv] -> Wqkv bf16, Wo -> bf16 ----
__global__ __launch_bounds__(256)
void cast_all(const float* __restrict__ x, const float* __restrict__ Wq,
              const float* __restrict__ Wk, const float* __restrict__ Wv,
              const float* __restrict__ Wo,
              __bf16* __restrict__ xb, __bf16* __restrict__ Wqkvb,
              __bf16* __restrict__ Wob)
{
    const size_t NX = (size_t)MTOT * DM;   // 4M
    const size_t NW = (size_t)DM * DM;     // 1M
    const size_t i = ((size_t)blockIdx.x * 256 + threadIdx.x) * 8;
    const float* src; __bf16* dst; size_t off;
    if (i < NX)               { src = x;  dst = xb;           off = i; }
    else if (i < NX + NW)     { src = Wq; dst = Wqkvb;        off = i - NX; }
    else if (i < NX + 2*NW)   { src = Wk; dst = Wqkvb + NW;   off = i - NX - NW; }
    else if (i < NX + 3*NW)   { src = Wv; dst = Wqkvb + 2*NW; off = i - NX - 2*NW; }
    else                      { src = Wo; dst = Wob;          off = i - NX - 3*NW; }
    const float4 f0 = *(const float4*)&src[off];
    const float4 f1 = *(const float4*)&src[off + 4];
    bf16x8 o;
    o[0] = (__bf16)f0.x; o[1] = (__bf16)f0.y; o[2] = (__bf16)f0.z; o[3] = (__bf16)f0.w;
    o[4] = (__bf16)f1.x; o[5] = (__bf16)f1.y; o[6] = (__bf16)f1.z; o[7] = (__bf16)f1.w;
    *(bf16x8*)&dst[off] = o;
}

// ---------------- MFMA GEMM: C[m,n] = sum_k A[m,k]*W[n,k], K=1024 ---------
// BM x BN tile, BK=64, 4 waves in 2x2 (wave-tile BM/2 x BN/2).
// LDS granules (16B) XOR-swizzled: global granule g of row r at slot g^(r&7)
// -> fragment ds_read_b128 spreads over all 8 bank groups (2-way = free).
// (256,4): VGPR cap 128 — kernel needs ~90; (256,6) clamped to 40 and
// spilled ~52 MB to scratch (R7 regression).
// MODE 0: QKV epilogue with FUSED RoPE (Q scaled by 0.125*log2e, base-2
// softmax domain); Q/K -> [b,h,s,d] bf16, V -> [b,h,d,s] bf16.
// MODE 1: plain fp32 C.
template<int BM, int BN, int MODE>
__global__ __launch_bounds__(256, 4)
void gemm_mfma(const __bf16* __restrict__ A, const __bf16* __restrict__ W,
               float* __restrict__ Cf,
               __bf16* __restrict__ Qb, __bf16* __restrict__ Kb,
               __bf16* __restrict__ Vtb)
{
    constexpr int IT = BM / 32;        // i-tiles per wave
    constexpr int JT = BN / 32;        // j-tiles per wave
    __shared__ __bf16 As[BM * 64];
    __shared__ __bf16 Bs[BN * 64];

    const int tid  = threadIdx.x;
    const int lane = tid & 63;
    const int wave = tid >> 6;
    const int ll   = lane & 15;
    const int quad = lane >> 4;
    const int wm   = (wave & 1) * (BM / 2);
    const int wn   = (wave >> 1) * (BN / 2);
    const int bm   = blockIdx.x * BM;
    const int bn   = blockIdx.y * BN;

    const __bf16* Ab = A + (size_t)bm * DM;
    const __bf16* Wb = W + (size_t)bn * DM;

    f32x4 acc[IT][JT];
#pragma unroll
    for (int i = 0; i < IT; i++)
#pragma unroll
        for (int j = 0; j < JT; j++) acc[i][j] = (f32x4){0.f, 0.f, 0.f, 0.f};

    for (int k0 = 0; k0 < DM; k0 += 64) {
#pragma unroll
        for (int j = 0; j < BM / 32; j++) {
            const int t = tid + 256 * j;
            const int r = t >> 3, g = t & 7;
            GLD16(Ab + (size_t)r * DM + k0 + ((g ^ (r & 7)) * 8), &As[t * 8]);
        }
#pragma unroll
        for (int j = 0; j < BN / 32; j++) {
            const int t = tid + 256 * j;
            const int r = t >> 3, g = t & 7;
            GLD16(Wb + (size_t)r * DM + k0 + ((g ^ (r & 7)) * 8), &Bs[t * 8]);
        }
        __syncthreads();   // drains vmcnt -> LDS tiles valid

#pragma unroll
        for (int kh = 0; kh < 2; kh++) {
            bf16x8 af[IT], bfr[JT];
#pragma unroll
            for (int i = 0; i < IT; i++) {
                const int r = wm + i*16 + ll;
                const int g = kh*4 + quad;
                af[i] = *(const bf16x8*)&As[(r*8 + (g ^ (r & 7))) * 8];
            }
#pragma unroll
            for (int j = 0; j < JT; j++) {
                const int r = wn + j*16 + ll;
                const int g = kh*4 + quad;
                bfr[j] = *(const bf16x8*)&Bs[(r*8 + (g ^ (r & 7))) * 8];
            }
#pragma unroll
            for (int i = 0; i < IT; i++)
#pragma unroll
                for (int j = 0; j < JT; j++)
                    acc[i][j] = __builtin_amdgcn_mfma_f32_16x16x32_bf16(
                        af[i], bfr[j], acc[i][j], 0, 0, 0);
        }
        __syncthreads();
    }

    if (MODE == 1) {
#pragma unroll
        for (int i = 0; i < IT; i++) {
#pragma unroll
            for (int j = 0; j < JT; j++) {
                const int gc = bn + wn + j*16 + ll;
#pragma unroll
                for (int r = 0; r < 4; r++) {
                    const int gr = bm + wm + i*16 + quad*4 + r;
                    Cf[(size_t)gr * DM + gc] = acc[i][j][r];
                }
            }
        }
    } else {
        const int which = bn >> 10;    // 0=Q 1=K 2=V (BN | 1024)
        const int nb = bn & 1023;
#pragma unroll
        for (int i = 0; i < IT; i++) {
            const int m0 = bm + wm + i*16 + quad*4;
            const int b  = m0 >> 11;
            const int s0 = m0 & (SEQ - 1);
#pragma unroll
            for (int j = 0; j < JT; j++) {
                const int n_g = nb + wn + j*16 + ll;
                const int h = n_g >> 6, d = n_g & (HD - 1);
                if (which == 2) {
                    bf16x4 pk;
#pragma unroll
                    for (int r = 0; r < 4; r++) pk[r] = (__bf16)acc[i][j][r];
                    *(bf16x4*)&Vtb[((size_t)((b*NHEADS + h)*HD + d)) * SEQ + s0] = pk;
                } else {
                    // fused RoPE: pair (d even, d odd) sits in lanes (ll, ll^1)
                    __bf16* P = (which == 0) ? Qb : Kb;
                    const float sc = (which == 0) ? 0.125f * LOG2E : 1.0f;
                    const float inv =
                        exp2f(-(float)(d & ~1) * (13.287712379549449f / 64.0f));
                    const bool odd = (d & 1);
#pragma unroll
                    for (int r = 0; r < 4; r++) {
                        const float own = acc[i][j][r];
                        const float oth = __shfl_xor(own, 1);
                        float sn, cs;
                        __sincosf((float)(s0 + r) * inv, &sn, &cs);
                        const float xe = odd ? oth : own;
                        const float xo = odd ? own : oth;
                        const float o = odd ? (xe * sn + xo * cs)
                                            : (xe * cs - xo * sn);
                        P[((size_t)(b*NHEADS + h) * SEQ + s0 + r) * HD + d] =
                            (__bf16)(o * sc);
                    }
                }
            }
        }
    }
}

// ---------------- MFMA flash attention, K-split waves, no-max softmax -----
// grid (32 bh, 16, 2): q-block = z ? 31-y : y. Flat-id round-robin gives
// each CU blocks {y0+1, y0+9, 32-y0, 24-y0} tile-units = exactly 66 — perfect
// balance at 4 blocks/CU (VGPR 128, LDS ~28 KB). Wave w owns k-tiles
// w, w+4, ... privately; scores bounded -> no running max; cross-wave combine
// is a plain sum, done 16 columns at a time through a small comb buffer.
__global__ __launch_bounds__(256, 4)
void attn_mfma(const __bf16* __restrict__ Qb, const __bf16* __restrict__ Kb,
               const __bf16* __restrict__ Vtb, __bf16* __restrict__ AOb)
{
    __shared__ __align__(16) __bf16 pt[4][16][LDP];   // 9.2 KB P round-trip
    __shared__ float comb[4][64][17];                 // 17.4 KB (stride 17: ~2-way max)
    __shared__ float lbuf[4][64];                     // 1 KB

    const int tid  = threadIdx.x;
    const int wave = tid >> 6;
    const int lane = tid & 63;
    const int m    = lane & 15;
    const int quad = lane >> 4;
    const int bh   = blockIdx.x;
    const int b    = bh >> 4, h = bh & 15;
    const int qb   = blockIdx.z ? (SEQ/64 - 1) - (int)blockIdx.y : (int)blockIdx.y;
    const int q0   = qb * 64;

    const __bf16* Qp = Qb + (size_t)bh * SEQ * HD;
    const __bf16* Kp = Kb + (size_t)bh * SEQ * HD;
    const __bf16* Vp = Vtb + (size_t)bh * HD * SEQ;

    bf16x8 ones;
#pragma unroll
    for (int j = 0; j < 8; j++) ones[j] = (__bf16)1.0f;

    bf16x8 qf[4][2];
#pragma unroll
    for (int i = 0; i < 4; i++) {
        const __bf16* qp = Qp + (size_t)(q0 + i*16 + m) * HD + quad*8;
        qf[i][0] = *(const bf16x8*)qp;
        qf[i][1] = *(const bf16x8*)(qp + 32);
    }

    f32x4 acc[4][4];
    f32x4 l_acc[4];
#pragma unroll
    for (int i = 0; i < 4; i++) {
        l_acc[i] = (f32x4){0.f, 0.f, 0.f, 0.f};
#pragma unroll
        for (int nt = 0; nt < 4; nt++) acc[i][nt] = (f32x4){0.f, 0.f, 0.f, 0.f};
    }

    for (int t = wave; t <= qb; t += 4) {
        const int k0 = t * 64;
        const bool diag = (t == qb);   // wave-uniform

        bf16x8 kf[4][2], vf[4][2];
#pragma unroll
        for (int tk = 0; tk < 4; tk++) {
            const __bf16* kp = Kp + (size_t)(k0 + tk*16 + m) * HD + quad*8;
            kf[tk][0] = *(const bf16x8*)kp;
            kf[tk][1] = *(const bf16x8*)(kp + 32);
            const __bf16* vp = Vp + (size_t)(tk*16 + m) * SEQ + k0 + quad*8;
            vf[tk][0] = *(const bf16x8*)vp;
            vf[tk][1] = *(const bf16x8*)(vp + 32);
        }

#pragma unroll
        for (int i = 0; i < 4; i++) {
            f32x4 s[4];
#pragma unroll
            for (int tk = 0; tk < 4; tk++) {
                s[tk] = (f32x4){0.f, 0.f, 0.f, 0.f};
                s[tk] = __builtin_amdgcn_mfma_f32_16x16x32_bf16(
                    qf[i][0], kf[tk][0], s[tk], 0, 0, 0);
                s[tk] = __builtin_amdgcn_mfma_f32_16x16x32_bf16(
                    qf[i][1], kf[tk][1], s[tk], 0, 0, 0);
            }
#pragma unroll
            for (int tk = 0; tk < 4; tk++) {
#pragma unroll
                for (int r = 0; r < 4; r++) {
                    float sv = s[tk][r];
                    if (diag)
                        sv = (16*tk + m <= 16*i + quad*4 + r) ? sv : -INFINITY;
                    const float p = __builtin_amdgcn_exp2f(sv);
                    pt[wave][quad*4 + r][16*tk + m] = (__bf16)p;
                }
            }
            const bf16x8 af0 = *(const bf16x8*)&pt[wave][m][quad*8];
            const bf16x8 af1 = *(const bf16x8*)&pt[wave][m][32 + quad*8];
            l_acc[i] = __builtin_amdgcn_mfma_f32_16x16x32_bf16(
                af0, ones, l_acc[i], 0, 0, 0);
            l_acc[i] = __builtin_amdgcn_mfma_f32_16x16x32_bf16(
                af1, ones, l_acc[i], 0, 0, 0);
#pragma unroll
            for (int nt = 0; nt < 4; nt++) {
                acc[i][nt] = __builtin_amdgcn_mfma_f32_16x16x32_bf16(
                    af0, vf[nt][0], acc[i][nt], 0, 0, 0);
                acc[i][nt] = __builtin_amdgcn_mfma_f32_16x16x32_bf16(
                    af1, vf[nt][1], acc[i][nt], 0, 0, 0);
            }
        }
    }

    // ---- cross-wave combine: l first, then O 16 columns at a time ----
    if (m == 0) {
#pragma unroll
        for (int i = 0; i < 4; i++)
#pragma unroll
            for (int r = 0; r < 4; r++)
                lbuf[wave][i*16 + quad*4 + r] = l_acc[i][r];
    }
    __syncthreads();

    const int row = tid >> 2;          // 0..63
    const int c0  = (tid & 3) * 4;     // 0,4,8,12
    const float rl = 1.0f / (lbuf[0][row] + lbuf[1][row]
                           + lbuf[2][row] + lbuf[3][row]);
    __bf16* op = AOb + (size_t)(b * SEQ + q0 + row) * DM + h * HD;

#pragma unroll
    for (int nt = 0; nt < 4; nt++) {
#pragma unroll
        for (int i = 0; i < 4; i++)
#pragma unroll
            for (int r = 0; r < 4; r++)
                comb[wave][i*16 + quad*4 + r][m] = acc[i][nt][r];
        __syncthreads();
        bf16x4 ov;
#pragma unroll
        for (int cc = 0; cc < 4; cc++) {
            const int col = c0 + cc;
            const float o = comb[0][row][col] + comb[1][row][col]
                          + comb[2][row][col] + comb[3][row][col];
            ov[cc] = (__bf16)(o * rl);
        }
        *(bf16x4*)&op[nt*16 + c0] = ov;
        if (nt < 3) __syncthreads();   // comb reused next round
    }
}

extern "C" void kernel_launch(void* const* d_in, const int* in_sizes, int n_in,
                              void* d_out, int out_size, void* d_ws, size_t ws_size,
                              hipStream_t stream) {
    const float* x  = (const float*)d_in[0];
    const float* Wq = (const float*)d_in[1];
    const float* Wk = (const float*)d_in[2];
    const float* Wv = (const float*)d_in[3];
    const float* Wo = (const float*)d_in[4];
    float* out = (float*)d_out;

    char* ws = (char*)d_ws;
    __bf16* xb    = (__bf16*)ws;                            // 8 MB [4096,1024]
    __bf16* Wqkvb = (__bf16*)(ws + ((size_t)8  << 20));     // 6 MB [3072,1024]
    __bf16* Wob   = (__bf16*)(ws + ((size_t)14 << 20));     // 2 MB [1024,1024]
    __bf16* Qb    = (__bf16*)(ws + ((size_t)16 << 20));     // 8 MB [b,h,s,d]
    __bf16* Kb    = (__bf16*)(ws + ((size_t)24 << 20));     // 8 MB [b,h,s,d]
    __bf16* Vtb   = (__bf16*)(ws + ((size_t)32 << 20));     // 8 MB [b,h,d,s]
    __bf16* AOb   = (__bf16*)(ws + ((size_t)40 << 20));     // 8 MB [4096,1024]

    cast_all<<<4096, 256, 0, stream>>>(x, Wq, Wk, Wv, Wo, xb, Wqkvb, Wob);

    // fused QKV projection + RoPE: M=4096, N=3072
    gemm_mfma<64,128,0><<<dim3(MTOT/64, 3072/128), 256, 0, stream>>>(
        xb, Wqkvb, nullptr, Qb, Kb, Vtb);

    // causal MFMA flash attention -> bf16 AO; 4 blocks/CU, balanced
    attn_mfma<<<dim3(BATCH*NHEADS, SEQ/128, 2), 256, 0, stream>>>(
        Qb, Kb, Vtb, AOb);

    // output projection: M=4096, N=1024, fp32 out
    gemm_mfma<64,64,1><<<dim3(MTOT/64, DM/64), 256, 0, stream>>>(
        AOb, Wob, out, nullptr, nullptr, nullptr);
}

// Round 10
// 170.950 us; speedup vs baseline: 1.7844x; 1.7844x over previous
//
#include <hip/hip_runtime.h>
#include <math.h>

#define NHEADS 16
#define HD 64
#define SEQ 2048
#define BATCH 2
#define DM 1024
#define MTOT (BATCH*SEQ)   // 4096
#define LDP 72             // pt row stride (halfwords): b128 reads conflict-free

typedef __bf16 bf16x8 __attribute__((ext_vector_type(8)));
typedef __bf16 bf16x4 __attribute__((ext_vector_type(4)));
typedef float  f32x4  __attribute__((ext_vector_type(4)));

#define LOG2E 1.4426950408889634f

// async global->LDS, 16B per lane; LDS side is wave-uniform base + lane*16
#define GLD16(gp, lp) __builtin_amdgcn_global_load_lds( \
    (const __attribute__((address_space(1))) void*)(gp), \
    (__attribute__((address_space(3))) void*)(lp), 16, 0, 0)

// ---------------- cast: x -> bf16, [Wq;Wk;Wv] -> Wqkv bf16, Wo -> bf16 ----
__global__ __launch_bounds__(256)
void cast_all(const float* __restrict__ x, const float* __restrict__ Wq,
              const float* __restrict__ Wk, const float* __restrict__ Wv,
              const float* __restrict__ Wo,
              __bf16* __restrict__ xb, __bf16* __restrict__ Wqkvb,
              __bf16* __restrict__ Wob)
{
    const size_t NX = (size_t)MTOT * DM;   // 4M
    const size_t NW = (size_t)DM * DM;     // 1M
    const size_t i = ((size_t)blockIdx.x * 256 + threadIdx.x) * 8;
    const float* src; __bf16* dst; size_t off;
    if (i < NX)               { src = x;  dst = xb;           off = i; }
    else if (i < NX + NW)     { src = Wq; dst = Wqkvb;        off = i - NX; }
    else if (i < NX + 2*NW)   { src = Wk; dst = Wqkvb + NW;   off = i - NX - NW; }
    else if (i < NX + 3*NW)   { src = Wv; dst = Wqkvb + 2*NW; off = i - NX - 2*NW; }
    else                      { src = Wo; dst = Wob;          off = i - NX - 3*NW; }
    const float4 f0 = *(const float4*)&src[off];
    const float4 f1 = *(const float4*)&src[off + 4];
    bf16x8 o;
    o[0] = (__bf16)f0.x; o[1] = (__bf16)f0.y; o[2] = (__bf16)f0.z; o[3] = (__bf16)f0.w;
    o[4] = (__bf16)f1.x; o[5] = (__bf16)f1.y; o[6] = (__bf16)f1.z; o[7] = (__bf16)f1.w;
    *(bf16x8*)&dst[off] = o;
}

// ---------------- MFMA GEMM: C[m,n] = sum_k A[m,k]*W[n,k], K=1024 ---------
// BM x BN tile, BK=64, 4 waves in 2x2 (wave-tile BM/2 x BN/2).
// LDS granules (16B) XOR-swizzled: global granule g of row r at slot g^(r&7)
// -> fragment ds_read_b128 spreads over all 8 bank groups (2-way = free).
// (256,4): VGPR cap 128+ — kernel needs ~90 arch; DO NOT raise to (256,6):
// R7 clamped to 40 and spilled ~52 MB (FETCH/WRITE doubled).
// MODE 0: QKV epilogue with FUSED RoPE (Q scaled by 0.125*log2e, base-2
// softmax domain); Q/K -> [b,h,s,d] bf16, V -> [b,h,d,s] bf16.
// MODE 1: plain fp32 C.
template<int BM, int BN, int MODE>
__global__ __launch_bounds__(256, 4)
void gemm_mfma(const __bf16* __restrict__ A, const __bf16* __restrict__ W,
               float* __restrict__ Cf,
               __bf16* __restrict__ Qb, __bf16* __restrict__ Kb,
               __bf16* __restrict__ Vtb)
{
    constexpr int IT = BM / 32;        // i-tiles per wave
    constexpr int JT = BN / 32;        // j-tiles per wave
    __shared__ __bf16 As[BM * 64];
    __shared__ __bf16 Bs[BN * 64];

    const int tid  = threadIdx.x;
    const int lane = tid & 63;
    const int wave = tid >> 6;
    const int ll   = lane & 15;
    const int quad = lane >> 4;
    const int wm   = (wave & 1) * (BM / 2);
    const int wn   = (wave >> 1) * (BN / 2);
    const int bm   = blockIdx.x * BM;
    const int bn   = blockIdx.y * BN;

    const __bf16* Ab = A + (size_t)bm * DM;
    const __bf16* Wb = W + (size_t)bn * DM;

    f32x4 acc[IT][JT];
#pragma unroll
    for (int i = 0; i < IT; i++)
#pragma unroll
        for (int j = 0; j < JT; j++) acc[i][j] = (f32x4){0.f, 0.f, 0.f, 0.f};

    for (int k0 = 0; k0 < DM; k0 += 64) {
#pragma unroll
        for (int j = 0; j < BM / 32; j++) {
            const int t = tid + 256 * j;
            const int r = t >> 3, g = t & 7;
            GLD16(Ab + (size_t)r * DM + k0 + ((g ^ (r & 7)) * 8), &As[t * 8]);
        }
#pragma unroll
        for (int j = 0; j < BN / 32; j++) {
            const int t = tid + 256 * j;
            const int r = t >> 3, g = t & 7;
            GLD16(Wb + (size_t)r * DM + k0 + ((g ^ (r & 7)) * 8), &Bs[t * 8]);
        }
        __syncthreads();   // drains vmcnt -> LDS tiles valid

#pragma unroll
        for (int kh = 0; kh < 2; kh++) {
            bf16x8 af[IT], bfr[JT];
#pragma unroll
            for (int i = 0; i < IT; i++) {
                const int r = wm + i*16 + ll;
                const int g = kh*4 + quad;
                af[i] = *(const bf16x8*)&As[(r*8 + (g ^ (r & 7))) * 8];
            }
#pragma unroll
            for (int j = 0; j < JT; j++) {
                const int r = wn + j*16 + ll;
                const int g = kh*4 + quad;
                bfr[j] = *(const bf16x8*)&Bs[(r*8 + (g ^ (r & 7))) * 8];
            }
#pragma unroll
            for (int i = 0; i < IT; i++)
#pragma unroll
                for (int j = 0; j < JT; j++)
                    acc[i][j] = __builtin_amdgcn_mfma_f32_16x16x32_bf16(
                        af[i], bfr[j], acc[i][j], 0, 0, 0);
        }
        __syncthreads();
    }

    if (MODE == 1) {
#pragma unroll
        for (int i = 0; i < IT; i++) {
#pragma unroll
            for (int j = 0; j < JT; j++) {
                const int gc = bn + wn + j*16 + ll;
#pragma unroll
                for (int r = 0; r < 4; r++) {
                    const int gr = bm + wm + i*16 + quad*4 + r;
                    Cf[(size_t)gr * DM + gc] = acc[i][j][r];
                }
            }
        }
    } else {
        const int which = bn >> 10;    // 0=Q 1=K 2=V (BN | 1024)
        const int nb = bn & 1023;
#pragma unroll
        for (int i = 0; i < IT; i++) {
            const int m0 = bm + wm + i*16 + quad*4;
            const int b  = m0 >> 11;
            const int s0 = m0 & (SEQ - 1);
#pragma unroll
            for (int j = 0; j < JT; j++) {
                const int n_g = nb + wn + j*16 + ll;
                const int h = n_g >> 6, d = n_g & (HD - 1);
                if (which == 2) {
                    bf16x4 pk;
#pragma unroll
                    for (int r = 0; r < 4; r++) pk[r] = (__bf16)acc[i][j][r];
                    *(bf16x4*)&Vtb[((size_t)((b*NHEADS + h)*HD + d)) * SEQ + s0] = pk;
                } else {
                    // fused RoPE: pair (d even, d odd) sits in lanes (ll, ll^1)
                    __bf16* P = (which == 0) ? Qb : Kb;
                    const float sc = (which == 0) ? 0.125f * LOG2E : 1.0f;
                    const float inv =
                        exp2f(-(float)(d & ~1) * (13.287712379549449f / 64.0f));
                    const bool odd = (d & 1);
#pragma unroll
                    for (int r = 0; r < 4; r++) {
                        const float own = acc[i][j][r];
                        const float oth = __shfl_xor(own, 1);
                        float sn, cs;
                        __sincosf((float)(s0 + r) * inv, &sn, &cs);
                        const float xe = odd ? oth : own;
                        const float xo = odd ? own : oth;
                        const float o = odd ? (xe * sn + xo * cs)
                                            : (xe * cs - xo * sn);
                        P[((size_t)(b*NHEADS + h) * SEQ + s0 + r) * HD + d] =
                            (__bf16)(o * sc);
                    }
                }
            }
        }
    }
}

// ---------------- MFMA flash attention, K-split waves, no-max softmax -----
// grid (32 bh, 16, 2): q-block = z ? 31-y : y — flat-id round-robin gives
// each CU ~66 tile-units total (balanced). Wave w owns k-tiles w, w+4, ...
// privately; scores bounded -> no running max; cross-wave combine is a plain
// sum, 16 columns at a time through a small comb buffer (LDS 27.6 KB).
// __launch_bounds__(256,2): cap 256 regs. (256,4) caps at 128 unified and
// spills ~600 MB to scratch (R9: 44.7 -> 153 us). NEVER raise this.
__global__ __launch_bounds__(256, 2)
void attn_mfma(const __bf16* __restrict__ Qb, const __bf16* __restrict__ Kb,
               const __bf16* __restrict__ Vtb, __bf16* __restrict__ AOb)
{
    __shared__ __align__(16) __bf16 pt[4][16][LDP];   // 9.2 KB P round-trip
    __shared__ float comb[4][64][17];                 // 17.4 KB
    __shared__ float lbuf[4][64];                     // 1 KB

    const int tid  = threadIdx.x;
    const int wave = tid >> 6;
    const int lane = tid & 63;
    const int m    = lane & 15;
    const int quad = lane >> 4;
    const int bh   = blockIdx.x;
    const int b    = bh >> 4, h = bh & 15;
    const int qb   = blockIdx.z ? (SEQ/64 - 1) - (int)blockIdx.y : (int)blockIdx.y;
    const int q0   = qb * 64;

    const __bf16* Qp = Qb + (size_t)bh * SEQ * HD;
    const __bf16* Kp = Kb + (size_t)bh * SEQ * HD;
    const __bf16* Vp = Vtb + (size_t)bh * HD * SEQ;

    bf16x8 ones;
#pragma unroll
    for (int j = 0; j < 8; j++) ones[j] = (__bf16)1.0f;

    bf16x8 qf[4][2];
#pragma unroll
    for (int i = 0; i < 4; i++) {
        const __bf16* qp = Qp + (size_t)(q0 + i*16 + m) * HD + quad*8;
        qf[i][0] = *(const bf16x8*)qp;
        qf[i][1] = *(const bf16x8*)(qp + 32);
    }

    f32x4 acc[4][4];
    f32x4 l_acc[4];
#pragma unroll
    for (int i = 0; i < 4; i++) {
        l_acc[i] = (f32x4){0.f, 0.f, 0.f, 0.f};
#pragma unroll
        for (int nt = 0; nt < 4; nt++) acc[i][nt] = (f32x4){0.f, 0.f, 0.f, 0.f};
    }

    for (int t = wave; t <= qb; t += 4) {
        const int k0 = t * 64;
        const bool diag = (t == qb);   // wave-uniform

        bf16x8 kf[4][2], vf[4][2];
#pragma unroll
        for (int tk = 0; tk < 4; tk++) {
            const __bf16* kp = Kp + (size_t)(k0 + tk*16 + m) * HD + quad*8;
            kf[tk][0] = *(const bf16x8*)kp;
            kf[tk][1] = *(const bf16x8*)(kp + 32);
            const __bf16* vp = Vp + (size_t)(tk*16 + m) * SEQ + k0 + quad*8;
            vf[tk][0] = *(const bf16x8*)vp;
            vf[tk][1] = *(const bf16x8*)(vp + 32);
        }

#pragma unroll
        for (int i = 0; i < 4; i++) {
            f32x4 s[4];
#pragma unroll
            for (int tk = 0; tk < 4; tk++) {
                s[tk] = (f32x4){0.f, 0.f, 0.f, 0.f};
                s[tk] = __builtin_amdgcn_mfma_f32_16x16x32_bf16(
                    qf[i][0], kf[tk][0], s[tk], 0, 0, 0);
                s[tk] = __builtin_amdgcn_mfma_f32_16x16x32_bf16(
                    qf[i][1], kf[tk][1], s[tk], 0, 0, 0);
            }
#pragma unroll
            for (int tk = 0; tk < 4; tk++) {
#pragma unroll
                for (int r = 0; r < 4; r++) {
                    float sv = s[tk][r];
                    if (diag)
                        sv = (16*tk + m <= 16*i + quad*4 + r) ? sv : -INFINITY;
                    const float p = __builtin_amdgcn_exp2f(sv);
                    pt[wave][quad*4 + r][16*tk + m] = (__bf16)p;
                }
            }
            const bf16x8 af0 = *(const bf16x8*)&pt[wave][m][quad*8];
            const bf16x8 af1 = *(const bf16x8*)&pt[wave][m][32 + quad*8];
            l_acc[i] = __builtin_amdgcn_mfma_f32_16x16x32_bf16(
                af0, ones, l_acc[i], 0, 0, 0);
            l_acc[i] = __builtin_amdgcn_mfma_f32_16x16x32_bf16(
                af1, ones, l_acc[i], 0, 0, 0);
#pragma unroll
            for (int nt = 0; nt < 4; nt++) {
                acc[i][nt] = __builtin_amdgcn_mfma_f32_16x16x32_bf16(
                    af0, vf[nt][0], acc[i][nt], 0, 0, 0);
                acc[i][nt] = __builtin_amdgcn_mfma_f32_16x16x32_bf16(
                    af1, vf[nt][1], acc[i][nt], 0, 0, 0);
            }
        }
    }

    // ---- cross-wave combine: l first, then O 16 columns at a time ----
    if (m == 0) {
#pragma unroll
        for (int i = 0; i < 4; i++)
#pragma unroll
            for (int r = 0; r < 4; r++)
                lbuf[wave][i*16 + quad*4 + r] = l_acc[i][r];
    }
    __syncthreads();

    const int row = tid >> 2;          // 0..63
    const int c0  = (tid & 3) * 4;     // 0,4,8,12
    const float rl = 1.0f / (lbuf[0][row] + lbuf[1][row]
                           + lbuf[2][row] + lbuf[3][row]);
    __bf16* op = AOb + (size_t)(b * SEQ + q0 + row) * DM + h * HD;

#pragma unroll
    for (int nt = 0; nt < 4; nt++) {
#pragma unroll
        for (int i = 0; i < 4; i++)
#pragma unroll
            for (int r = 0; r < 4; r++)
                comb[wave][i*16 + quad*4 + r][m] = acc[i][nt][r];
        __syncthreads();
        bf16x4 ov;
#pragma unroll
        for (int cc = 0; cc < 4; cc++) {
            const int col = c0 + cc;
            const float o = comb[0][row][col] + comb[1][row][col]
                          + comb[2][row][col] + comb[3][row][col];
            ov[cc] = (__bf16)(o * rl);
        }
        *(bf16x4*)&op[nt*16 + c0] = ov;
        if (nt < 3) __syncthreads();   // comb reused next round
    }
}

extern "C" void kernel_launch(void* const* d_in, const int* in_sizes, int n_in,
                              void* d_out, int out_size, void* d_ws, size_t ws_size,
                              hipStream_t stream) {
    const float* x  = (const float*)d_in[0];
    const float* Wq = (const float*)d_in[1];
    const float* Wk = (const float*)d_in[2];
    const float* Wv = (const float*)d_in[3];
    const float* Wo = (const float*)d_in[4];
    float* out = (float*)d_out;

    char* ws = (char*)d_ws;
    __bf16* xb    = (__bf16*)ws;                            // 8 MB [4096,1024]
    __bf16* Wqkvb = (__bf16*)(ws + ((size_t)8  << 20));     // 6 MB [3072,1024]
    __bf16* Wob   = (__bf16*)(ws + ((size_t)14 << 20));     // 2 MB [1024,1024]
    __bf16* Qb    = (__bf16*)(ws + ((size_t)16 << 20));     // 8 MB [b,h,s,d]
    __bf16* Kb    = (__bf16*)(ws + ((size_t)24 << 20));     // 8 MB [b,h,s,d]
    __bf16* Vtb   = (__bf16*)(ws + ((size_t)32 << 20));     // 8 MB [b,h,d,s]
    __bf16* AOb   = (__bf16*)(ws + ((size_t)40 << 20));     // 8 MB [4096,1024]

    cast_all<<<4096, 256, 0, stream>>>(x, Wq, Wk, Wv, Wo, xb, Wqkvb, Wob);

    // fused QKV projection + RoPE: M=4096, N=3072
    gemm_mfma<64,128,0><<<dim3(MTOT/64, 3072/128), 256, 0, stream>>>(
        xb, Wqkvb, nullptr, Qb, Kb, Vtb);

    // causal MFMA flash attention -> bf16 AO; balanced 1024-block grid
    attn_mfma<<<dim3(BATCH*NHEADS, SEQ/128, 2), 256, 0, stream>>>(
        Qb, Kb, Vtb, AOb);

    // output projection: M=4096, N=1024, fp32 out
    gemm_mfma<64,64,1><<<dim3(MTOT/64, DM/64), 256, 0, stream>>>(
        AOb, Wob, out, nullptr, nullptr, nullptr);
}